// Round 1
// baseline (332.916 us; speedup 1.0000x reference)
//
#include <hip/hip_runtime.h>

#define HW 512
#define TW 64
#define TH 32
#define STR 68   // LDS row stride (floats): mult of 4 for 16B align, breaks pow2 bank patterns

// cos(2*pi*t/8)/sqrt(8), sin(2*pi*t/8)/sqrt(8)
__device__ constexpr float CT[8] = {0.3535533906f, 0.25f, 0.0f, -0.25f,
                                    -0.3535533906f, -0.25f, 0.0f, 0.25f};
__device__ constexpr float STt[8] = {0.0f, 0.25f, 0.3535533906f, 0.25f,
                                     0.0f, -0.25f, -0.3535533906f, -0.25f};

__device__ __forceinline__ int reflect512(int v) {
    v = v < 0 ? -v : v;
    v = v > 511 ? 1022 - v : v;
    return v;
}

__device__ __forceinline__ float softt(float x) {
    return copysignf(fmaxf(fabsf(x) - 0.05f, 0.0f), x);
}

__device__ __forceinline__ void haar_quad(float a, float b, float c, float d,
                                          float& oa, float& ob, float& oc, float& od) {
    float LL = (a + b + c + d) * 0.5f;
    float LH = (a + b - c - d) * 0.5f;
    float HL = (a - b + c - d) * 0.5f;
    float HH = (a - b - c + d) * 0.5f;
    LH = softt(LH); HL = softt(HL); HH = softt(HH);
    oa = (LL + LH + HL + HH) * 0.5f;
    ob = (LL + LH - HL - HH) * 0.5f;
    oc = (LL - LH + HL - HH) * 0.5f;
    od = (LL - LH - HL + HH) * 0.5f;
}

__launch_bounds__(256, 4)
__global__ void sas_fused(const float* __restrict__ in, float* __restrict__ out) {
    // sIn: (TH+2)x(TW+2) halo tile; later reused as T and then rec (TH*STR <= 34*STR)
    __shared__ float sIn[34 * STR];
    __shared__ float sBlur[TH * STR];
    __shared__ float sP[TH * STR];
    __shared__ float sQ[TH * STR];

    const int tid = threadIdx.x;
    const int p = blockIdx.y;            // plane 0..95 (b*3+c)
    const int tile = blockIdx.x;         // 0..127
    const int tx0 = (tile & 7) * TW;
    const int ty0 = (tile >> 3) * TH;
    const float* __restrict__ inP = in + (size_t)p * (HW * HW);

    // ---- Phase 1: load halo tile with reflect padding ----
    for (int k = tid; k < 34 * 66; k += 256) {
        int r = k / 66;
        int c = k - r * 66;
        int gy = reflect512(ty0 + r - 1);
        int gx = reflect512(tx0 + c - 1);
        sIn[r * STR + c] = inP[gy * HW + gx];
    }
    __syncthreads();

    // ---- Phase 2: separable 3x3 gaussian (sigma=0.8) ----
    {
        const float e = 0.45783335f;                 // exp(-1/1.28)
        const float inv_s = 1.0f / ((1.0f + 2.0f * e) * (1.0f + 2.0f * e));
        const int i = tid & 31;                      // output row
        const int seg = tid >> 5;                    // 8-col segment
        const float* r0 = &sIn[(i + 0) * STR + 8 * seg];
        const float* r1 = &sIn[(i + 1) * STR + 8 * seg];
        const float* r2 = &sIn[(i + 2) * STR + 8 * seg];
        float v[10];
#pragma unroll
        for (int k = 0; k < 10; ++k)
            v[k] = e * (r0[k] + r2[k]) + r1[k];
        float* w = &sBlur[i * STR + 8 * seg];
#pragma unroll
        for (int k = 0; k < 8; ++k)
            w[k] = (e * (v[k] + v[k + 2]) + v[k + 1]) * inv_s;
    }
    __syncthreads();

    float* const sT = sIn;  // T / rec reuse region (32*STR floats)

    // ---- row pass: P = X*C, Q = X*S (contract along x within 8x8 block) ----
    auto rowpass = [&](const float* __restrict__ src) {
        const int m = tid & 31;    // row
        const int bx = tid >> 5;   // block-col 0..7
        const float* x = &src[m * STR + 8 * bx];
        float xv[8];
#pragma unroll
        for (int n = 0; n < 8; ++n) xv[n] = x[n];
        float* pd = &sP[m * STR + 8 * bx];
        float* qd = &sQ[m * STR + 8 * bx];
#pragma unroll
        for (int v = 0; v < 8; ++v) {
            float pp = 0.0f, qq = 0.0f;
#pragma unroll
            for (int n = 0; n < 8; ++n) {
                pp += xv[n] * CT[(n * v) & 7];
                qq += xv[n] * STt[(n * v) & 7];
            }
            pd[v] = pp;
            qd[v] = qq;
        }
    };

    // ---- col pass: dst = C*P - S*Q (contract along y within 8x8 block) ----
    auto colpass = [&](float* __restrict__ dst, bool nonlin) {
        const int v = tid & 63;    // column
        const int g = tid >> 6;    // block-row 0..3
        float pm[8], qm[8];
#pragma unroll
        for (int m = 0; m < 8; ++m) {
            pm[m] = sP[(8 * g + m) * STR + v];
            qm[m] = sQ[(8 * g + m) * STR + v];
        }
#pragma unroll
        for (int u = 0; u < 8; ++u) {
            float t = 0.0f;
#pragma unroll
            for (int m = 0; m < 8; ++m)
                t += pm[m] * CT[(u * m) & 7] - qm[m] * STt[(u * m) & 7];
            if (nonlin) {
                float ca = fabsf(t);
                t = (ca < 2.5f) ? t * (ca * 0.4f) : t;
                t = fminf(fmaxf(t, -10.0f), 10.0f);
            }
            dst[(8 * g + u) * STR + v] = t;
        }
    };

    rowpass(sBlur);            __syncthreads();
    colpass(sT, true);         __syncthreads();   // forward + nonlinearity -> T
    rowpass(sT);               __syncthreads();
    colpass(sT, false);        __syncthreads();   // inverse -> rec (I_d) in sT

    // ---- Phase 7: residual + Haar refine + store ----
    {
        const int qx = tid & 15;       // 4-col group
        const int qy = tid >> 4;       // 0..15 (row pair)
        const int y0 = 2 * qy, y1 = y0 + 1;
        const int x0 = 4 * qx;
        float4 d0 = *(const float4*)&sT[y0 * STR + x0];
        float4 d1 = *(const float4*)&sT[y1 * STR + x0];
        float4 g0 = *(const float4*)&sBlur[y0 * STR + x0];
        float4 g1 = *(const float4*)&sBlur[y1 * STR + x0];
        float4 r0 = make_float4(g0.x - d0.x, g0.y - d0.y, g0.z - d0.z, g0.w - d0.w);
        float4 r1 = make_float4(g1.x - d1.x, g1.y - d1.y, g1.z - d1.z, g1.w - d1.w);

        const int chId = (p / 3) * 6 + (p % 3);
        float* __restrict__ oI = out + ((size_t)chId << 18);
        float* __restrict__ oR = out + ((size_t)(chId + 3) << 18);
        const size_t base = (size_t)(ty0 + y0) * HW + (tx0 + x0);

        float4 w0, w1;
        haar_quad(d0.x, d0.y, d1.x, d1.y, w0.x, w0.y, w1.x, w1.y);
        haar_quad(d0.z, d0.w, d1.z, d1.w, w0.z, w0.w, w1.z, w1.w);
        *(float4*)&oI[base] = w0;
        *(float4*)&oI[base + HW] = w1;

        haar_quad(r0.x, r0.y, r1.x, r1.y, w0.x, w0.y, w1.x, w1.y);
        haar_quad(r0.z, r0.w, r1.z, r1.w, w0.z, w0.w, w1.z, w1.w);
        *(float4*)&oR[base] = w0;
        *(float4*)&oR[base + HW] = w1;
    }
}

extern "C" void kernel_launch(void* const* d_in, const int* in_sizes, int n_in,
                              void* d_out, int out_size, void* d_ws, size_t ws_size,
                              hipStream_t stream) {
    const float* I = (const float*)d_in[0];
    float* out = (float*)d_out;
    dim3 grid(128, 96);   // 8x16 tiles per 512x512 plane, 96 planes
    sas_fused<<<grid, dim3(256), 0, stream>>>(I, out);
}

// Round 2
// 279.280 us; speedup vs baseline: 1.1921x; 1.1921x over previous
//
#include <hip/hip_runtime.h>

#define HW 512

__device__ __forceinline__ int reflect512(int v) {
    v = v < 0 ? -v : v;
    v = v > 511 ? 1022 - v : v;
    return v;
}

__device__ __forceinline__ float softt(float x) {
    return copysignf(fmaxf(fabsf(x) - 0.05f, 0.0f), x);
}

__device__ __forceinline__ void haar_quad(float a, float b, float c, float d,
                                          float& oa, float& ob, float& oc, float& od) {
    float LL = (a + b + c + d) * 0.5f;
    float LH = (a + b - c - d) * 0.5f;
    float HL = (a - b + c - d) * 0.5f;
    float HH = (a - b - c + d) * 0.5f;
    LH = softt(LH); HL = softt(HL); HH = softt(HH);
    oa = (LL + LH + HL + HH) * 0.5f;
    ob = (LL + LH - HL - HH) * 0.5f;
    oc = (LL - LH + HL - HH) * 0.5f;
    od = (LL - LH - HL + HH) * 0.5f;
}

// 8-point real-DFT butterflies (ortho): out[v] = sum_n x[n] * {cos,sin}(2*pi*n*v/8)/sqrt(8)
#define RA 0.35355339059327373f
#define RB 0.25f

__device__ __forceinline__ void dft8_cos(const float* __restrict__ x, float* __restrict__ P) {
    float e0 = x[0] + x[4], d0 = x[0] - x[4];
    float e1 = x[2] + x[6];
    float o0 = x[1] + x[5], m0 = x[1] - x[5];
    float o1 = x[3] + x[7], m1 = x[3] - x[7];
    float see = e0 + e1, dee = e0 - e1, soo = o0 + o1;
    float dd = m0 - m1;
    P[0] = RA * (see + soo);
    P[4] = RA * (see - soo);
    float p2 = RA * dee;
    P[2] = p2; P[6] = p2;
    float t0 = RA * d0, t1 = RB * dd;
    P[1] = t0 + t1; P[7] = t0 + t1;
    P[3] = t0 - t1; P[5] = t0 - t1;
}

__device__ __forceinline__ void dft8_sin(const float* __restrict__ x, float* __restrict__ Q) {
    float d1 = x[2] - x[6];
    float o0 = x[1] + x[5], m0 = x[1] - x[5];
    float o1 = x[3] + x[7], m1 = x[3] - x[7];
    float qq = m0 + m1;
    Q[0] = 0.0f; Q[4] = 0.0f;
    float q2 = RA * (o0 - o1);
    Q[2] = q2; Q[6] = -q2;
    float t0 = RB * qq, t1 = RA * d1;
    Q[1] = t0 + t1; Q[7] = -(t0 + t1);
    Q[3] = t0 - t1; Q[5] = -(t0 - t1);
}

__launch_bounds__(256, 2)
__global__ void sas_fused(const float* __restrict__ in, float* __restrict__ out) {
    const int lane = threadIdx.x & 63;   // block-col 0..63
    const int wv = threadIdx.x >> 6;     // wave in workgroup
    const int p = blockIdx.y;            // plane (b*3+c)
    const int by = blockIdx.x * 4 + wv;  // block-row 0..63
    const float* __restrict__ inP = in + (size_t)p * (HW * HW);
    const int cx = lane * 8;

    // ---- load 10 rows x own-8-cols (coalesced: a wave reads a full 512-float row) ----
    float4 va[10], vb[10];
#pragma unroll
    for (int j = 0; j < 10; ++j) {
        int gy = reflect512(by * 8 - 1 + j);
        const float* r = inP + (size_t)gy * HW + cx;
        va[j] = *(const float4*)r;
        vb[j] = *(const float4*)(r + 4);
    }

    // ---- assemble 10x10 (x-halo via cross-lane shuffle; reflect at image edges) ----
    float x[10][10];
#pragma unroll
    for (int j = 0; j < 10; ++j) {
        float lft = __shfl_up(vb[j].w, 1);    // neighbor's col 7
        float rgt = __shfl_down(va[j].x, 1);  // neighbor's col 0
        if (lane == 0)  lft = va[j].y;        // reflect(-1) = col 1
        if (lane == 63) rgt = vb[j].z;        // reflect(512) = col 510
        x[j][0] = lft;
        x[j][1] = va[j].x; x[j][2] = va[j].y; x[j][3] = va[j].z; x[j][4] = va[j].w;
        x[j][5] = vb[j].x; x[j][6] = vb[j].y; x[j][7] = vb[j].z; x[j][8] = vb[j].w;
        x[j][9] = rgt;
    }

    // ---- separable 3x3 gaussian, sigma=0.8 ----
    const float e = 0.45783336f;                  // exp(-1/1.28)
    const float inv_s = 1.0f / ((1.0f + 2.0f * e) * (1.0f + 2.0f * e));
    float B[8][8];
#pragma unroll
    for (int j = 0; j < 8; ++j) {
        float v[10];
#pragma unroll
        for (int c = 0; c < 10; ++c)
            v[c] = e * (x[j][c] + x[j + 2][c]) + x[j + 1][c];
#pragma unroll
        for (int c = 0; c < 8; ++c)
            B[j][c] = (e * (v[c] + v[c + 2]) + v[c + 1]) * inv_s;
    }

    // ---- forward transform T = C*B*C - S*B*S, with nonlinearity; then same inverse ----
    float P[8][8], Q[8][8];
#pragma unroll
    for (int m = 0; m < 8; ++m) { dft8_cos(B[m], P[m]); dft8_sin(B[m], Q[m]); }
#pragma unroll
    for (int v = 0; v < 8; ++v) {
        float pc[8], qc[8], tc[8], sc[8];
#pragma unroll
        for (int m = 0; m < 8; ++m) { pc[m] = P[m][v]; qc[m] = Q[m][v]; }
        dft8_cos(pc, tc);
        dft8_sin(qc, sc);
#pragma unroll
        for (int u = 0; u < 8; ++u) {
            float t = tc[u] - sc[u];
            float ca = fabsf(t);
            t = (ca < 2.5f) ? t * (ca * 0.4f) : t;
            t = fminf(fmaxf(t, -10.0f), 10.0f);
            P[u][v] = t;   // T lives in P
        }
    }
#pragma unroll
    for (int m = 0; m < 8; ++m) {
        float tr[8];
#pragma unroll
        for (int n = 0; n < 8; ++n) tr[n] = P[m][n];
        dft8_cos(tr, P[m]);
        dft8_sin(tr, Q[m]);
    }
#pragma unroll
    for (int v = 0; v < 8; ++v) {
        float pc[8], qc[8], tc[8], sc[8];
#pragma unroll
        for (int m = 0; m < 8; ++m) { pc[m] = P[m][v]; qc[m] = Q[m][v]; }
        dft8_cos(pc, tc);
        dft8_sin(qc, sc);
#pragma unroll
        for (int u = 0; u < 8; ++u) P[u][v] = tc[u] - sc[u];   // rec (I_d) lives in P
    }

    // ---- residual + Haar refine on both streams + coalesced stores ----
    const int chId = (p / 3) * 6 + (p % 3);
    float* __restrict__ oI = out + ((size_t)chId << 18);
    float* __restrict__ oR = out + ((size_t)(chId + 3) << 18);
#pragma unroll
    for (int qy = 0; qy < 4; ++qy) {
        float ti[2][8], tr_[2][8];
#pragma unroll
        for (int qx = 0; qx < 4; ++qx) {
            float d00 = P[2*qy][2*qx],   d01 = P[2*qy][2*qx+1];
            float d10 = P[2*qy+1][2*qx], d11 = P[2*qy+1][2*qx+1];
            haar_quad(d00, d01, d10, d11,
                      ti[0][2*qx], ti[0][2*qx+1], ti[1][2*qx], ti[1][2*qx+1]);
            float r00 = B[2*qy][2*qx]   - d00, r01 = B[2*qy][2*qx+1]   - d01;
            float r10 = B[2*qy+1][2*qx] - d10, r11 = B[2*qy+1][2*qx+1] - d11;
            haar_quad(r00, r01, r10, r11,
                      tr_[0][2*qx], tr_[0][2*qx+1], tr_[1][2*qx], tr_[1][2*qx+1]);
        }
        size_t base = (size_t)(by * 8 + 2 * qy) * HW + cx;
        *(float4*)&oI[base]          = make_float4(ti[0][0], ti[0][1], ti[0][2], ti[0][3]);
        *(float4*)&oI[base + 4]      = make_float4(ti[0][4], ti[0][5], ti[0][6], ti[0][7]);
        *(float4*)&oI[base + HW]     = make_float4(ti[1][0], ti[1][1], ti[1][2], ti[1][3]);
        *(float4*)&oI[base + HW + 4] = make_float4(ti[1][4], ti[1][5], ti[1][6], ti[1][7]);
        *(float4*)&oR[base]          = make_float4(tr_[0][0], tr_[0][1], tr_[0][2], tr_[0][3]);
        *(float4*)&oR[base + 4]      = make_float4(tr_[0][4], tr_[0][5], tr_[0][6], tr_[0][7]);
        *(float4*)&oR[base + HW]     = make_float4(tr_[1][0], tr_[1][1], tr_[1][2], tr_[1][3]);
        *(float4*)&oR[base + HW + 4] = make_float4(tr_[1][4], tr_[1][5], tr_[1][6], tr_[1][7]);
    }
}

extern "C" void kernel_launch(void* const* d_in, const int* in_sizes, int n_in,
                              void* d_out, int out_size, void* d_ws, size_t ws_size,
                              hipStream_t stream) {
    const float* I = (const float*)d_in[0];
    float* out = (float*)d_out;
    dim3 grid(16, 96);   // 16 workgroups x 4 waves = 64 block-rows per plane; 96 planes
    sas_fused<<<grid, dim3(256), 0, stream>>>(I, out);
}